// Round 9
// baseline (212.790 us; speedup 1.0000x reference)
//
#include <hip/hip_runtime.h>
#include <hip/hip_bf16.h>
#include <math.h>

#define NN 325
#define FD 64
#define KH 4
#define DH 16
#define BT 192
#define NN2 (NN*NN)
#define PST (NN*DH)     // 5200 elems per (slot) slice
#define BTN 336         // biasT n-dim (padded)
#define BTH (336*336)   // biasT per-head floats
#define VTS  352        // vT row stride (bf16)
#define VSLICE (16*VTS) // vT per-(h,bt) slice
#define PSTR 344        // attn wave-private P row stride (bf16, 16B-aligned)
#define HSTR 72         // ffn LDS stride (bf16)
#define NPROJ 975
#define NBIAS 144       // 4 h x 36 tiles of 64x64
#define NPAD  (KH*BT)   // 768
#define LOG2E 1.44269504088896f

typedef __attribute__((ext_vector_type(8))) short short8;
typedef __attribute__((ext_vector_type(4))) float f32x4;

union U8 { uint4 u; short8 s; ushort us[8]; };
__device__ inline short8 lds8(const ushort* p){ U8 t; t.u = *(const uint4*)p; return t.s; }
__device__ inline float b2f(ushort v){ return __uint_as_float(((unsigned)v) << 16); }
__device__ inline ushort f2b(float f){
  unsigned u = __float_as_uint(f);
  u += 0x7fff + ((u >> 16) & 1);
  return (ushort)(u >> 16);
}
__device__ inline unsigned pk2(float a, float b){
  union { __hip_bfloat162 h; unsigned u; } t;
  t.h = __float22bfloat162_rn(float2{a, b});
  return t.u;
}
__device__ inline short8 cvt8(const float* p){
  float4 u = ((const float4*)p)[0], v = ((const float4*)p)[1];
  U8 t;
  t.us[0]=f2b(u.x); t.us[1]=f2b(u.y); t.us[2]=f2b(u.z); t.us[3]=f2b(u.w);
  t.us[4]=f2b(v.x); t.us[5]=f2b(v.y); t.us[6]=f2b(v.z); t.us[7]=f2b(v.w);
  return t.s;
}

// ---------------- wpack: W's -> Wcat bf16 [448][64] + bcat ----------------
__global__ __launch_bounds__(256) void wpack_kernel(
    const float* __restrict__ Wq,  const float* __restrict__ bq,
    const float* __restrict__ Wk,  const float* __restrict__ bk,
    const float* __restrict__ Wks, const float* __restrict__ bks,
    const float* __restrict__ Wv,  const float* __restrict__ bv,
    const float* __restrict__ Wvs, const float* __restrict__ bvs,
    const float* __restrict__ Wf1, const float* __restrict__ Wf2,
    ushort* __restrict__ Wcat, float* __restrict__ bcat){
  int blk = blockIdx.x;
  const float* Ws[7] = {Wq, Wk, Wks, Wv, Wvs, Wf1, Wf2};
  const float* bs[5] = {bq, bk, bks, bv, bvs};
  int f = blk * 64 + (threadIdx.x >> 2);
  int c0 = (threadIdx.x & 3) * 8;
  const float* wr = Ws[blk] + (f & 63) * 64;
  unsigned* dst = (unsigned*)Wcat + f * 32 + c0;
  #pragma unroll
  for (int c = 0; c < 8; ++c)
    dst[c] = f2b(wr[2*(c0+c)]) | ((unsigned)f2b(wr[2*(c0+c)+1]) << 16);
  if (blk < 5 && (threadIdx.x & 3) == 0) bcat[f] = bs[blk][f & 63];
}

// ---------------- prep: proj (V->vt direct) | biasT tiles | vt pad zero ----------------
// proj slots: q=h, k=4+h, ks=8+h, vs=12+h  (V never lands in proj)
__global__ __launch_bounds__(256) void prep_kernel(
    const float* __restrict__ x, const ushort* __restrict__ Wcat,
    const float* __restrict__ bcat, ushort* __restrict__ proj,
    ushort* __restrict__ vt,
    const float* __restrict__ Wdi, const float* __restrict__ Wdo,
    const float* __restrict__ A,   const float* __restrict__ AT,
    float* __restrict__ biasT){
  __shared__ float tile[64 * 65];
  int bid = blockIdx.x, tid = threadIdx.x;
  if (bid < NPROJ){
    // ---- projections via MFMA (A=W rows, B=x rows) ----
    int lane = tid & 63, wid = tid >> 6;
    int r0 = bid * 64 + wid * 16;
    int m = lane & 15, g = lane >> 4;
    int gr = r0 + m;
    int bt = gr / NN, n = gr - bt * NN;
    const float* xr = x + (size_t)gr * 64 + g * 8;
    short8 xb0 = cvt8(xr);
    short8 xb1 = cvt8(xr + 32);
    for (int ct = 0; ct < 20; ++ct){
      short8 w0 = lds8(Wcat + ((size_t)(ct*16 + m) * 64 + g * 8));
      short8 w1 = lds8(Wcat + ((size_t)(ct*16 + m) * 64 + g * 8 + 32));
      float4 b4 = *(const float4*)(bcat + ct*16 + 4*g);
      f32x4 acc = {b4.x, b4.y, b4.z, b4.w};
      acc = __builtin_amdgcn_mfma_f32_16x16x32_bf16(w0, xb0, acc, 0, 0, 0);
      acc = __builtin_amdgcn_mfma_f32_16x16x32_bf16(w1, xb1, acc, 0, 0, 0);
      if (ct >= 12 && ct < 16){
        // V head (ct-12): write transposed directly to vt[d][n]
        ushort* vs = vt + (size_t)((ct-12)*BT + bt) * VSLICE + n;
        #pragma unroll
        for (int rg = 0; rg < 4; ++rg)
          vs[(size_t)(4*g + rg) * VTS] = f2b(acc[rg]);
      } else {
        int slot = (ct < 12) ? ct : ct - 4;
        // fold 1/sqrt(D) AND log2(e) into Q (softmax runs on exp2)
        float sc = (ct < 4) ? 0.25f * LOG2E : 1.0f;
        uint2 w;
        w.x = pk2(acc[0]*sc, acc[1]*sc);
        w.y = pk2(acc[2]*sc, acc[3]*sc);
        *(uint2*)(proj + ((size_t)slot * BT + bt) * PST + n*16 + 4*g) = w;
      }
    }
  } else if (bid < NPROJ + NBIAS){
    // ---- biasT[h][m][n] (x log2e), col-masked; LDS tile transpose ----
    int tb = bid - NPROJ;
    int h = tb / 36, rem = tb - h * 36;
    int nt = rem / 6, mt = rem - nt * 6;
    int n0 = nt * 64, m0 = mt * 64;
    #pragma unroll
    for (int i = 0; i < 16; ++i){
      int idx = i * 256 + tid;
      int nn = idx >> 6, mm = idx & 63;
      int n = n0 + nn, mc = m0 + mm;
      float s;
      if (mc >= NN) s = -1e30f;
      else if (n >= NN) s = 0.f;
      else {
        int r = n * NN + mc;
        s = 0.f;
        if (h < 2){
          #pragma unroll
          for (int k = 0; k < 3; ++k) s += Wdi[(h*3 + k)*NN2 + r] * A[k*NN2 + r];
        } else {
          int h2 = h - 2;
          #pragma unroll
          for (int k = 0; k < 3; ++k) s += Wdo[(h2*3 + k)*NN2 + r] * AT[k*NN2 + r];
        }
        s *= LOG2E;
      }
      tile[mm * 65 + nn] = s;
    }
    __syncthreads();
    #pragma unroll
    for (int i = 0; i < 16; ++i){
      int idx = i * 256 + tid;
      int mm = idx >> 6, nn = idx & 63;
      int gm = m0 + mm, gn = n0 + nn;
      if (gm < BTN && gn < BTN)
        biasT[(size_t)h * BTH + (size_t)gm * BTN + gn] = tile[mm * 65 + nn];
    }
  } else {
    // ---- vt pad: zero cols 325..351 for one (h,bt) slice ----
    int slice = bid - NPROJ - NBIAS;
    ushort* vs = vt + (size_t)slice * VSLICE;
    if (tid < 432){
      int d = tid / 27, c = NN + tid % 27;
      vs[(size_t)d * VTS + c] = 0;
    }
  }
}

// ---------------- attention: ONE WAVE per (h,bt,qt); zero barriers ----------------
__global__ __launch_bounds__(64) void attn_kernel(
    const ushort* __restrict__ proj, const float* __restrict__ biasT,
    const ushort* __restrict__ vt, ushort* __restrict__ val){
  __shared__ ushort P[16 * PSTR];      // wave-private P (bf16, row-major)
  int bhid = blockIdx.x, qt = blockIdx.y;
  int h = bhid / BT, bt = bhid - h * BT;
  int lane = threadIdx.x & 63;
  int m = lane & 15, g = lane >> 4;
  const ushort* qb  = proj + (size_t)(( 0 + h)*BT + bt) * PST;
  const ushort* kb  = proj + (size_t)(( 4 + h)*BT + bt) * PST;
  const ushort* ksb = proj + (size_t)(( 8 + h)*BT + bt) * PST;
  const ushort* vsb = proj + (size_t)((12 + h)*BT + bt) * PST;
  const ushort* vtg = vt + (size_t)(h*BT + bt) * VSLICE;
  short8 zero = {0,0,0,0,0,0,0,0};

  // Q fragment + epilogue scalars (rows owned by this lane: qt*16 + g*4 + rg)
  short8 aq = (g < 2) ? lds8(qb + ((size_t)(qt*16 + m) * 16 + g * 8)) : zero;
  float qv[4], kv[4], vsv[4];
  #pragma unroll
  for (int rg = 0; rg < 4; ++rg){
    int nn = min(qt*16 + g*4 + rg, NN - 1);
    qv[rg]  = b2f(qb [(size_t)nn * 16 + m]);
    kv[rg]  = b2f(ksb[(size_t)nn * 16 + m]);
    vsv[rg] = b2f(vsb[(size_t)nn * 16 + m]);
  }

  // ---- stream S: MFMA -> +biasT -> exp2 -> pack P (wave-private, no barrier) ----
  const float* bTc = biasT + (size_t)h * BTH + qt*16 + g*4;
  float sm[4] = {0.f, 0.f, 0.f, 0.f};
  for (int ct = 0; ct < 21; ++ct){
    int col = ct*16 + m;
    short8 kf = (g < 2) ? lds8(kb + ((size_t)col * 16 + g * 8)) : zero;
    f32x4 s = {0.f, 0.f, 0.f, 0.f};
    s = __builtin_amdgcn_mfma_f32_16x16x32_bf16(aq, kf, s, 0, 0, 0);
    float4 b4 = *(const float4*)(bTc + (size_t)col * BTN);
    float e0 = __builtin_amdgcn_exp2f(s[0] + b4.x);
    float e1 = __builtin_amdgcn_exp2f(s[1] + b4.y);
    float e2 = __builtin_amdgcn_exp2f(s[2] + b4.z);
    float e3 = __builtin_amdgcn_exp2f(s[3] + b4.w);
    sm[0] += e0; sm[1] += e1; sm[2] += e2; sm[3] += e3;
    P[(g*4 + 0) * PSTR + col] = f2b(e0);
    P[(g*4 + 1) * PSTR + col] = f2b(e1);
    P[(g*4 + 2) * PSTR + col] = f2b(e2);
    P[(g*4 + 3) * PSTR + col] = f2b(e3);
  }

  // ---- row-sum + sigmoid-dot reductions (within 16 m-lanes of this g-group) ----
  float dp[4];
  #pragma unroll
  for (int rg = 0; rg < 4; ++rg) dp[rg] = qv[rg] * kv[rg];
  #pragma unroll
  for (int o = 1; o <= 8; o <<= 1){
    #pragma unroll
    for (int rg = 0; rg < 4; ++rg){
      sm[rg] += __shfl_xor(sm[rg], o, 64);
      dp[rg] += __shfl_xor(dp[rg], o, 64);
    }
  }

  // ---- PV from wave-private P (in-wave LDS ordering only) ----
  asm volatile("s_waitcnt lgkmcnt(0)" ::: "memory");
  const ushort* prow = P + (size_t)m * PSTR;
  f32x4 acc = {0.f, 0.f, 0.f, 0.f};
  #pragma unroll
  for (int tt = 0; tt < 11; ++tt){
    short8 ap = (tt == 10 && g >= 2) ? zero : lds8(prow + tt*32 + g*8);
    short8 bv = lds8(vtg + (size_t)m * VTS + tt*32 + g*8);
    acc = __builtin_amdgcn_mfma_f32_16x16x32_bf16(ap, bv, acc, 0, 0, 0);
  }

  // ---- epilogue: lane owns (rows g*4+rg, d=m) ----
  #pragma unroll
  for (int rg = 0; rg < 4; ++rg){
    int n = qt*16 + g*4 + rg;
    if (n < NN){
      float esv = __builtin_amdgcn_rcpf(1.f + __builtin_amdgcn_exp2f(-dp[rg]));
      float iv  = __builtin_amdgcn_rcpf(esv + sm[rg]);
      float res = acc[rg] * iv + (1.f - sm[rg] * iv) * vsv[rg];
      val[((size_t)bt * NN + n) * FD + h*16 + m] = f2b(res);
    }
  }
}

// ---------------- FFN + residual + LayerNorm (swapped operands, no barrier) ----------------
__global__ __launch_bounds__(256) void ffn_kernel(
    const ushort* __restrict__ val, const float* __restrict__ x,
    const ushort* __restrict__ Wf1b, const float* __restrict__ bf1,
    const ushort* __restrict__ Wf2b, const float* __restrict__ bf2,
    const float* __restrict__ g_ln, const float* __restrict__ b_ln,
    float* __restrict__ out){
  __shared__ ushort hs[4][16 * HSTR];   // wave-private slices
  int tid = threadIdx.x, lane = tid & 63, wid = tid >> 6;
  int m = lane & 15, g = lane >> 4;
  int r0 = blockIdx.x * 64 + wid * 16;
  int row = r0 + m;

  short8 vb0 = lds8(val + ((size_t)row * 64 + g * 8));
  short8 vb1 = lds8(val + ((size_t)row * 64 + g * 8 + 32));

  #pragma unroll
  for (int ct = 0; ct < 4; ++ct){
    short8 w0 = lds8(Wf1b + ((size_t)(ct*16 + m) * 64 + g * 8));
    short8 w1 = lds8(Wf1b + ((size_t)(ct*16 + m) * 64 + g * 8 + 32));
    float4 b4 = *(const float4*)(bf1 + ct*16 + 4*g);
    f32x4 acc = {b4.x, b4.y, b4.z, b4.w};
    acc = __builtin_amdgcn_mfma_f32_16x16x32_bf16(w0, vb0, acc, 0, 0, 0);
    acc = __builtin_amdgcn_mfma_f32_16x16x32_bf16(w1, vb1, acc, 0, 0, 0);
    uint2 w;
    float g0 = 0.5f*acc[0]*(1.f + erff(acc[0]*0.70710678118654752f));
    float g1 = 0.5f*acc[1]*(1.f + erff(acc[1]*0.70710678118654752f));
    float g2 = 0.5f*acc[2]*(1.f + erff(acc[2]*0.70710678118654752f));
    float g3 = 0.5f*acc[3]*(1.f + erff(acc[3]*0.70710678118654752f));
    w.x = pk2(g0, g1); w.y = pk2(g2, g3);
    *(uint2*)&hs[wid][m * HSTR + ct*16 + 4*g] = w;
  }
  asm volatile("s_waitcnt lgkmcnt(0)" ::: "memory");
  short8 h0 = lds8(&hs[wid][m * HSTR + g * 8]);
  short8 h1 = lds8(&hs[wid][m * HSTR + g * 8 + 32]);

  float t[4][4];
  #pragma unroll
  for (int ct = 0; ct < 4; ++ct){
    short8 w0 = lds8(Wf2b + ((size_t)(ct*16 + m) * 64 + g * 8));
    short8 w1 = lds8(Wf2b + ((size_t)(ct*16 + m) * 64 + g * 8 + 32));
    float4 b4 = *(const float4*)(bf2 + ct*16 + 4*g);
    f32x4 acc = {b4.x, b4.y, b4.z, b4.w};
    acc = __builtin_amdgcn_mfma_f32_16x16x32_bf16(w0, h0, acc, 0, 0, 0);
    acc = __builtin_amdgcn_mfma_f32_16x16x32_bf16(w1, h1, acc, 0, 0, 0);
    float4 xr = *(const float4*)(x + (size_t)row * 64 + ct*16 + 4*g);
    t[ct][0] = acc[0] + xr.x; t[ct][1] = acc[1] + xr.y;
    t[ct][2] = acc[2] + xr.z; t[ct][3] = acc[3] + xr.w;
  }
  float s = 0.f;
  #pragma unroll
  for (int ct = 0; ct < 4; ++ct) s += (t[ct][0]+t[ct][1]) + (t[ct][2]+t[ct][3]);
  s += __shfl_xor(s, 16, 64); s += __shfl_xor(s, 32, 64);
  float mu = s * (1.f/64.f);
  float v = 0.f;
  #pragma unroll
  for (int ct = 0; ct < 4; ++ct){
    #pragma unroll
    for (int rg = 0; rg < 4; ++rg){ float d = t[ct][rg] - mu; v += d*d; }
  }
  v += __shfl_xor(v, 16, 64); v += __shfl_xor(v, 32, 64);
  float rs = rsqrtf(v * (1.f/64.f) + 1e-5f);
  #pragma unroll
  for (int ct = 0; ct < 4; ++ct){
    float4 g4 = *(const float4*)(g_ln + ct*16 + 4*g);
    float4 bb = *(const float4*)(b_ln + ct*16 + 4*g);
    float4 o;
    o.x = g4.x*(t[ct][0]-mu)*rs + bb.x;
    o.y = g4.y*(t[ct][1]-mu)*rs + bb.y;
    o.z = g4.z*(t[ct][2]-mu)*rs + bb.z;
    o.w = g4.w*(t[ct][3]-mu)*rs + bb.w;
    *(float4*)(out + (size_t)row * 64 + ct*16 + 4*g) = o;
  }
}

extern "C" void kernel_launch(void* const* d_in, const int* in_sizes, int n_in,
                              void* d_out, int out_size, void* d_ws, size_t ws_size,
                              hipStream_t stream) {
  const float* x    = (const float*)d_in[0];
  const float* A    = (const float*)d_in[1];
  const float* AT   = (const float*)d_in[2];
  const float* Wq   = (const float*)d_in[3];
  const float* bq   = (const float*)d_in[4];
  const float* Wk   = (const float*)d_in[5];
  const float* bk   = (const float*)d_in[6];
  const float* Wks  = (const float*)d_in[7];
  const float* bks  = (const float*)d_in[8];
  const float* Wv   = (const float*)d_in[9];
  const float* bv   = (const float*)d_in[10];
  const float* Wvs  = (const float*)d_in[11];
  const float* bvs  = (const float*)d_in[12];
  const float* Wdi  = (const float*)d_in[13];
  const float* Wdo  = (const float*)d_in[14];
  const float* Wf1  = (const float*)d_in[15];
  const float* bf1  = (const float*)d_in[16];
  const float* Wf2  = (const float*)d_in[17];
  const float* bf2  = (const float*)d_in[18];
  const float* g_ln = (const float*)d_in[19];
  const float* b_ln = (const float*)d_in[20];
  float* out = (float*)d_out;

  float* ws = (float*)d_ws;
  // layout (float units):
  // proj (bf16, 16 slots x 192 x 5200 = 15,974,400 el) : [0, 7,987,200)
  // biasT(fp32, 4 x 336 x 336 = 451,584)               : [7,987,200, 8,438,784)
  // val  (bf16, 3,993,600 el)                          : [8,438,784, 10,435,584)
  // vt   (bf16, 4,325,376 el)                          : [10,435,584, 12,598,272)
  // Wcat (bf16, 28,672 el)                             : [12,598,272, 12,612,608)
  // bcat (fp32, 320)                                   : [12,612,608, 12,612,928)
  ushort* proj  = (ushort*)ws;
  float*  biasT = ws + 7987200;
  ushort* val   = (ushort*)(ws + 8438784);
  ushort* vt    = (ushort*)(ws + 10435584);
  ushort* Wcat  = (ushort*)(ws + 12598272);
  float*  bcat  = ws + 12612608;
  ushort* Wf1b  = Wcat + 320*64;
  ushort* Wf2b  = Wcat + 384*64;

  wpack_kernel<<<7, 256, 0, stream>>>(Wq, bq, Wk, bk, Wks, bks,
                                      Wv, bv, Wvs, bvs, Wf1, Wf2, Wcat, bcat);
  prep_kernel<<<NPROJ + NBIAS + NPAD, 256, 0, stream>>>(
      x, Wcat, bcat, proj, vt, Wdi, Wdo, A, AT, biasT);
  attn_kernel<<<dim3(KH*BT, 21), 64, 0, stream>>>(proj, biasT, vt, val);
  ffn_kernel<<<975, 256, 0, stream>>>(val, x, Wf1b, bf1, Wf2b, bf2,
                                      g_ln, b_ln, out);
}

// Round 10
// 198.875 us; speedup vs baseline: 1.0700x; 1.0700x over previous
//
#include <hip/hip_runtime.h>
#include <hip/hip_bf16.h>
#include <math.h>

#define NN 325
#define FD 64
#define KH 4
#define DH 16
#define BT 192
#define NN2 (NN*NN)
#define PST (NN*DH)     // 5200 elems per (proj,head,bt) slice
#define SSTR 340        // attn S row stride (dwords)
#define BSTR 352        // padded bias row stride (floats)
#define VTS  352        // vT row stride (bf16)
#define VSLICE (16*VTS) // vT per-(h,bt) slice
#define HSTR 72         // ffn LDS stride (bf16)
#define NPROJ 975
#define NBIAS 447       // ceil(4*325*352/4 / 256) vectorized x4
#define NPAD  (KH*BT)   // 768
#define LOG2E 1.44269504088896f

typedef __attribute__((ext_vector_type(8))) short short8;
typedef __attribute__((ext_vector_type(4))) float f32x4;

union U8 { uint4 u; short8 s; ushort us[8]; };
__device__ inline short8 lds8(const ushort* p){ U8 t; t.u = *(const uint4*)p; return t.s; }
__device__ inline float b2f(ushort v){ return __uint_as_float(((unsigned)v) << 16); }
__device__ inline ushort f2b(float f){
  unsigned u = __float_as_uint(f);
  u += 0x7fff + ((u >> 16) & 1);
  return (ushort)(u >> 16);
}
__device__ inline unsigned pk2(float a, float b){
  union { __hip_bfloat162 h; unsigned u; } t;
  t.h = __float22bfloat162_rn(float2{a, b});
  return t.u;
}
__device__ inline short8 cvt8(const float* p){
  float4 u = ((const float4*)p)[0], v = ((const float4*)p)[1];
  U8 t;
  t.us[0]=f2b(u.x); t.us[1]=f2b(u.y); t.us[2]=f2b(u.z); t.us[3]=f2b(u.w);
  t.us[4]=f2b(v.x); t.us[5]=f2b(v.y); t.us[6]=f2b(v.z); t.us[7]=f2b(v.w);
  return t.s;
}
// fast GELU: x * sigmoid(1.702 x), on v_exp_f32/v_rcp_f32 (1.702*log2e = 2.455467)
__device__ inline float gelu_f(float x){
  return x * __builtin_amdgcn_rcpf(1.f + __builtin_amdgcn_exp2f(-2.45546699f * x));
}

// ---------------- wpack: W's -> Wcat bf16 [448][64] + bcat ----------------
__global__ __launch_bounds__(256) void wpack_kernel(
    const float* __restrict__ Wq,  const float* __restrict__ bq,
    const float* __restrict__ Wk,  const float* __restrict__ bk,
    const float* __restrict__ Wks, const float* __restrict__ bks,
    const float* __restrict__ Wv,  const float* __restrict__ bv,
    const float* __restrict__ Wvs, const float* __restrict__ bvs,
    const float* __restrict__ Wf1, const float* __restrict__ Wf2,
    ushort* __restrict__ Wcat, float* __restrict__ bcat){
  int blk = blockIdx.x;
  const float* Ws[7] = {Wq, Wk, Wks, Wv, Wvs, Wf1, Wf2};
  const float* bs[5] = {bq, bk, bks, bv, bvs};
  int f = blk * 64 + (threadIdx.x >> 2);
  int c0 = (threadIdx.x & 3) * 8;
  const float* wr = Ws[blk] + (f & 63) * 64;
  unsigned* dst = (unsigned*)Wcat + f * 32 + c0;
  #pragma unroll
  for (int c = 0; c < 8; ++c)
    dst[c] = f2b(wr[2*(c0+c)]) | ((unsigned)f2b(wr[2*(c0+c)+1]) << 16);
  if (blk < 5 && (threadIdx.x & 3) == 0) bcat[f] = bs[blk][f & 63];
}

// ---------------- prep: proj (+V->vt direct) | bias padded x4 | vt pad zero ----------------
__global__ __launch_bounds__(256) void prep_kernel(
    const float* __restrict__ x, const ushort* __restrict__ Wcat,
    const float* __restrict__ bcat, ushort* __restrict__ proj,
    ushort* __restrict__ vt,
    const float* __restrict__ Wdi, const float* __restrict__ Wdo,
    const float* __restrict__ A,   const float* __restrict__ AT,
    float* __restrict__ biasP){
  int bid = blockIdx.x, tid = threadIdx.x;
  if (bid < NPROJ){
    // ---- projections via MFMA (A=W rows, B=x rows) ----
    int lane = tid & 63, wid = tid >> 6;
    int r0 = bid * 64 + wid * 16;
    int m = lane & 15, g = lane >> 4;
    int gr = r0 + m;
    int bt = gr / NN, n = gr - bt * NN;
    const float* xr = x + (size_t)gr * 64 + g * 8;
    short8 xb0 = cvt8(xr);
    short8 xb1 = cvt8(xr + 32);
    for (int ct = 0; ct < 20; ++ct){
      short8 w0 = lds8(Wcat + ((size_t)(ct*16 + m) * 64 + g * 8));
      short8 w1 = lds8(Wcat + ((size_t)(ct*16 + m) * 64 + g * 8 + 32));
      float4 b4 = *(const float4*)(bcat + ct*16 + 4*g);
      f32x4 acc = {b4.x, b4.y, b4.z, b4.w};
      acc = __builtin_amdgcn_mfma_f32_16x16x32_bf16(w0, xb0, acc, 0, 0, 0);
      acc = __builtin_amdgcn_mfma_f32_16x16x32_bf16(w1, xb1, acc, 0, 0, 0);
      if (ct >= 12 && ct < 16){
        // V head (ct-12): write transposed directly to vt[d][n]
        ushort* vs = vt + (size_t)((ct-12)*BT + bt) * VSLICE + n;
        #pragma unroll
        for (int rg = 0; rg < 4; ++rg)
          vs[(size_t)(4*g + rg) * VTS] = f2b(acc[rg]);
      } else {
        // fold 1/sqrt(D) AND log2(e) into Q (softmax runs on exp2)
        float sc = (ct < 4) ? 0.25f * LOG2E : 1.0f;
        uint2 w;
        w.x = pk2(acc[0]*sc, acc[1]*sc);
        w.y = pk2(acc[2]*sc, acc[3]*sc);
        *(uint2*)(proj + ((size_t)ct * BT + bt) * PST + n*16 + 4*g) = w;
      }
    }
  } else if (bid < NPROJ + NBIAS){
    // ---- bias padded [4][325][352] x log2e (4 elems/thread), pad = -1e30 ----
    int base = ((bid - NPROJ) * 256 + tid) * 4;
    if (base >= KH * NN * BSTR) return;
    int h = base / (NN * BSTR), rem = base - h * (NN * BSTR);
    int n = rem / BSTR, m = rem - n * BSTR;
    const float* Wp = (h < 2) ? Wdi + (size_t)h*3*NN2 : Wdo + (size_t)(h-2)*3*NN2;
    const float* Ap = (h < 2) ? A : AT;
    float4 o;
    #pragma unroll
    for (int i = 0; i < 4; ++i){
      float s = -1e30f;
      int mc = m + i;
      if (mc < NN){
        int r = n * NN + mc;
        s = (Wp[r] * Ap[r] + Wp[NN2 + r] * Ap[NN2 + r]
           + Wp[2*NN2 + r] * Ap[2*NN2 + r]) * LOG2E;
      }
      (&o.x)[i] = s;
    }
    *(float4*)(biasP + base) = o;
  } else {
    // ---- vt pad: zero cols 325..351 for one (h,bt) slice ----
    int slice = bid - NPROJ - NBIAS;
    ushort* vs = vt + (size_t)slice * VSLICE;
    if (tid < 432){
      int d = tid / 27, c = NN + tid % 27;
      vs[(size_t)d * VTS + c] = 0;
    }
  }
}

// ---------------- attention: block per (bhid, qt); all global loads prefetched ----------------
__global__ __launch_bounds__(256, 4) void attn_kernel(
    const ushort* __restrict__ proj, const float* __restrict__ biasP,
    const ushort* __restrict__ vt, ushort* __restrict__ val){
  __shared__ float S[16 * SSTR];       // fp32 scores; P in-place bf16
  __shared__ float part[4][16][16];
  __shared__ float rstat[16][2];
  int bhid = blockIdx.x, qt = blockIdx.y;
  int h = bhid / BT, bt = bhid - h * BT;
  int tid = threadIdx.x, lane = tid & 63, wid = tid >> 6;
  const ushort* qb  = proj + (size_t)((0*KH + h)*BT + bt) * PST;
  const ushort* kb  = proj + (size_t)((1*KH + h)*BT + bt) * PST;
  const ushort* ksb = proj + (size_t)((2*KH + h)*BT + bt) * PST;
  const ushort* vsb = proj + (size_t)((4*KH + h)*BT + bt) * PST;
  const ushort* vtg = vt + (size_t)(h*BT + bt) * VSLICE;

  int m = lane & 15, g = lane >> 4;
  short8 zero = {0,0,0,0,0,0,0,0};

  // ---------- prefetch ALL global data up front ----------
  short8 aq = (g < 2) ? lds8(qb + ((size_t)(qt*16 + m) * 16 + g * 8)) : zero;
  short8 kf[6];
  #pragma unroll
  for (int i = 0; i < 6; ++i){
    int ct = wid + 4*i;
    kf[i] = (ct < 21 && g < 2) ? lds8(kb + ((size_t)(ct*16 + m) * 16 + g * 8)) : zero;
  }
  short8 vf[3];
  #pragma unroll
  for (int i = 0; i < 3; ++i){
    int tt = wid + 4*i;
    vf[i] = (tt < 11) ? lds8(vtg + (size_t)m * VTS + tt*32 + g*8) : zero;
  }
  int r = tid >> 4, c = tid & 15;
  int n = qt * 16 + r;
  int nb = min(n, NN - 1);
  const float* bp = biasP + (size_t)(h*NN + nb) * BSTR;
  float4 b4[6];
  #pragma unroll
  for (int j = 0; j < 6; ++j){
    int m0 = c * 4 + 64 * j;
    b4[j] = (m0 < 336) ? *(const float4*)(bp + m0) : make_float4(0.f,0.f,0.f,0.f);
  }
  float qv  = b2f(qb[(size_t)nb * 16 + c]);
  float kv  = b2f(ksb[(size_t)nb * 16 + c]);
  float vsv = b2f(vsb[(size_t)nb * 16 + c]);

  // ---------- phase 1: S = Q' K^T ----------
  #pragma unroll
  for (int i = 0; i < 6; ++i){
    int ct = wid + 4*i;
    if (ct < 21){
      f32x4 acc = {0.f, 0.f, 0.f, 0.f};
      acc = __builtin_amdgcn_mfma_f32_16x16x32_bf16(aq, kf[i], acc, 0, 0, 0);
      #pragma unroll
      for (int rg = 0; rg < 4; ++rg)
        S[(g*4 + rg)*SSTR + ct*16 + m] = acc[rg];
    }
  }
  __syncthreads();

  // ---------- phase 2: exp2 softmax, pack P in place (single pass) ----------
  {
    float* sr = S + r * SSTR;
    ushort* pr = (ushort*)sr;
    float sum = 0.f;
    #pragma unroll
    for (int j = 0; j < 6; ++j){
      int m0 = c * 4 + 64 * j;
      if (m0 < 336){
        float4 s4 = *(const float4*)(sr + m0);
        float e0 = __builtin_amdgcn_exp2f(s4.x + b4[j].x);
        float e1 = __builtin_amdgcn_exp2f(s4.y + b4[j].y);
        float e2 = __builtin_amdgcn_exp2f(s4.z + b4[j].z);
        float e3 = __builtin_amdgcn_exp2f(s4.w + b4[j].w);
        sum += (e0 + e1) + (e2 + e3);
        uint2 w;
        w.x = pk2(e0, e1);
        w.y = pk2(e2, e3);
        *(uint2*)(pr + m0) = w;
      }
    }
    float dp = qv * kv;
    dp += __shfl_xor(dp, 1, 64); dp += __shfl_xor(dp, 2, 64);
    dp += __shfl_xor(dp, 4, 64); dp += __shfl_xor(dp, 8, 64);
    sum += __shfl_xor(sum, 1, 64); sum += __shfl_xor(sum, 2, 64);
    sum += __shfl_xor(sum, 4, 64); sum += __shfl_xor(sum, 8, 64);
    if (c == 0){
      float esv = __builtin_amdgcn_rcpf(1.f + __builtin_amdgcn_exp2f(-dp));
      float iv  = __builtin_amdgcn_rcpf(esv + sum);
      rstat[r][0] = iv; rstat[r][1] = 1.f - sum * iv;
    }
  }
  __syncthreads();

  // ---------- phase 3: PV from prefetched vT fragments ----------
  {
    const ushort* prow = (const ushort*)S + (size_t)m * (SSTR * 2);
    f32x4 acc = {0.f, 0.f, 0.f, 0.f};
    #pragma unroll
    for (int i = 0; i < 3; ++i){
      int tt = wid + 4*i;
      if (tt < 11){
        short8 ap = (tt == 10 && g >= 2) ? zero : lds8(prow + tt*32 + g*8);
        acc = __builtin_amdgcn_mfma_f32_16x16x32_bf16(ap, vf[i], acc, 0, 0, 0);
      }
    }
    #pragma unroll
    for (int rg = 0; rg < 4; ++rg)
      part[wid][g*4 + rg][m] = acc[rg];
  }
  __syncthreads();

  // ---------- epilogue ----------
  if (n < NN){
    float s = part[0][r][c] + part[1][r][c] + part[2][r][c] + part[3][r][c];
    float res = s * rstat[r][0] + rstat[r][1] * vsv;
    val[((size_t)bt * NN + n) * FD + h * 16 + c] = f2b(res);
  }
}

// ---------------- FFN + residual + LayerNorm (swapped operands, no barrier) ----------------
__global__ __launch_bounds__(256) void ffn_kernel(
    const ushort* __restrict__ val, const float* __restrict__ x,
    const ushort* __restrict__ Wf1b, const float* __restrict__ bf1,
    const ushort* __restrict__ Wf2b, const float* __restrict__ bf2,
    const float* __restrict__ g_ln, const float* __restrict__ b_ln,
    float* __restrict__ out){
  __shared__ ushort hs[4][16 * HSTR];   // wave-private slices
  int tid = threadIdx.x, lane = tid & 63, wid = tid >> 6;
  int m = lane & 15, g = lane >> 4;
  int r0 = blockIdx.x * 64 + wid * 16;
  int row = r0 + m;

  short8 vb0 = lds8(val + ((size_t)row * 64 + g * 8));
  short8 vb1 = lds8(val + ((size_t)row * 64 + g * 8 + 32));

  #pragma unroll
  for (int ct = 0; ct < 4; ++ct){
    short8 w0 = lds8(Wf1b + ((size_t)(ct*16 + m) * 64 + g * 8));
    short8 w1 = lds8(Wf1b + ((size_t)(ct*16 + m) * 64 + g * 8 + 32));
    float4 b4 = *(const float4*)(bf1 + ct*16 + 4*g);
    f32x4 acc = {b4.x, b4.y, b4.z, b4.w};
    acc = __builtin_amdgcn_mfma_f32_16x16x32_bf16(w0, vb0, acc, 0, 0, 0);
    acc = __builtin_amdgcn_mfma_f32_16x16x32_bf16(w1, vb1, acc, 0, 0, 0);
    uint2 w;
    w.x = pk2(gelu_f(acc[0]), gelu_f(acc[1]));
    w.y = pk2(gelu_f(acc[2]), gelu_f(acc[3]));
    *(uint2*)&hs[wid][m * HSTR + ct*16 + 4*g] = w;
  }
  asm volatile("s_waitcnt lgkmcnt(0)" ::: "memory");
  short8 h0 = lds8(&hs[wid][m * HSTR + g * 8]);
  short8 h1 = lds8(&hs[wid][m * HSTR + g * 8 + 32]);

  float t[4][4];
  #pragma unroll
  for (int ct = 0; ct < 4; ++ct){
    short8 w0 = lds8(Wf2b + ((size_t)(ct*16 + m) * 64 + g * 8));
    short8 w1 = lds8(Wf2b + ((size_t)(ct*16 + m) * 64 + g * 8 + 32));
    float4 b4 = *(const float4*)(bf2 + ct*16 + 4*g);
    f32x4 acc = {b4.x, b4.y, b4.z, b4.w};
    acc = __builtin_amdgcn_mfma_f32_16x16x32_bf16(w0, h0, acc, 0, 0, 0);
    acc = __builtin_amdgcn_mfma_f32_16x16x32_bf16(w1, h1, acc, 0, 0, 0);
    float4 xr = *(const float4*)(x + (size_t)row * 64 + ct*16 + 4*g);
    t[ct][0] = acc[0] + xr.x; t[ct][1] = acc[1] + xr.y;
    t[ct][2] = acc[2] + xr.z; t[ct][3] = acc[3] + xr.w;
  }
  float s = 0.f;
  #pragma unroll
  for (int ct = 0; ct < 4; ++ct) s += (t[ct][0]+t[ct][1]) + (t[ct][2]+t[ct][3]);
  s += __shfl_xor(s, 16, 64); s += __shfl_xor(s, 32, 64);
  float mu = s * (1.f/64.f);
  float v = 0.f;
  #pragma unroll
  for (int ct = 0; ct < 4; ++ct){
    #pragma unroll
    for (int rg = 0; rg < 4; ++rg){ float d = t[ct][rg] - mu; v += d*d; }
  }
  v += __shfl_xor(v, 16, 64); v += __shfl_xor(v, 32, 64);
  float rs = rsqrtf(v * (1.f/64.f) + 1e-5f);
  #pragma unroll
  for (int ct = 0; ct < 4; ++ct){
    float4 g4 = *(const float4*)(g_ln + ct*16 + 4*g);
    float4 bb = *(const float4*)(b_ln + ct*16 + 4*g);
    float4 o;
    o.x = g4.x*(t[ct][0]-mu)*rs + bb.x;
    o.y = g4.y*(t[ct][1]-mu)*rs + bb.y;
    o.z = g4.z*(t[ct][2]-mu)*rs + bb.z;
    o.w = g4.w*(t[ct][3]-mu)*rs + bb.w;
    *(float4*)(out + (size_t)row * 64 + ct*16 + 4*g) = o;
  }
}

extern "C" void kernel_launch(void* const* d_in, const int* in_sizes, int n_in,
                              void* d_out, int out_size, void* d_ws, size_t ws_size,
                              hipStream_t stream) {
  const float* x    = (const float*)d_in[0];
  const float* A    = (const float*)d_in[1];
  const float* AT   = (const float*)d_in[2];
  const float* Wq   = (const float*)d_in[3];
  const float* bq   = (const float*)d_in[4];
  const float* Wk   = (const float*)d_in[5];
  const float* bk   = (const float*)d_in[6];
  const float* Wks  = (const float*)d_in[7];
  const float* bks  = (const float*)d_in[8];
  const float* Wv   = (const float*)d_in[9];
  const float* bv   = (const float*)d_in[10];
  const float* Wvs  = (const float*)d_in[11];
  const float* bvs  = (const float*)d_in[12];
  const float* Wdi  = (const float*)d_in[13];
  const float* Wdo  = (const float*)d_in[14];
  const float* Wf1  = (const float*)d_in[15];
  const float* bf1  = (const float*)d_in[16];
  const float* Wf2  = (const float*)d_in[17];
  const float* bf2  = (const float*)d_in[18];
  const float* g_ln = (const float*)d_in[19];
  const float* b_ln = (const float*)d_in[20];
  float* out = (float*)d_out;

  float* ws = (float*)d_ws;
  ushort* proj  = (ushort*)ws;                     // bf16, 19,968,000 el (slots 12-15 unused)
  float*  biasP = ws + 9984000;                    // fp32, 457,600
  ushort* val   = (ushort*)(ws + 10441600);        // bf16, 3,993,600 el
  ushort* vt    = (ushort*)(ws + 12438400);        // bf16, 4,325,376 el
  ushort* Wcat  = (ushort*)(ws + 14601088);        // bf16, 28,672 el
  float*  bcat  = ws + 14615424;                   // fp32, 320
  ushort* Wf1b  = Wcat + 320*64;
  ushort* Wf2b  = Wcat + 384*64;

  wpack_kernel<<<7, 256, 0, stream>>>(Wq, bq, Wk, bk, Wks, bks,
                                      Wv, bv, Wvs, bvs, Wf1, Wf2, Wcat, bcat);
  prep_kernel<<<NPROJ + NBIAS + NPAD, 256, 0, stream>>>(
      x, Wcat, bcat, proj, vt, Wdi, Wdo, A, AT, biasP);
  attn_kernel<<<dim3(KH*BT, 21), 256, 0, stream>>>(proj, biasP, vt, val);
  ffn_kernel<<<975, 256, 0, stream>>>(val, x, Wf1b, bf1, Wf2b, bf2,
                                      g_ln, b_ln, out);
}